// Round 7
// baseline (159.646 us; speedup 1.0000x reference)
//
#include <hip/hip_runtime.h>

#define B_N 524288
#define NTILES 2048   // 256 rows per tile
#define NBLK 768      // 3 blocks/CU * 256 CU: all co-resident (LDS-capped)

typedef __attribute__((ext_vector_type(8))) short bf16x8;
typedef __attribute__((ext_vector_type(16))) float f32x16;
typedef __attribute__((ext_vector_type(4))) int i32x4;

#define GLOBAL_AS __attribute__((address_space(1)))
#define LDS_AS __attribute__((address_space(3)))

// ws blob layout (ushort units):
//   W2 frags: [ ((c*9+s)*64 + lane)*8 + j ]  -> 4*9*64*8 = 18432
//   W3 frags: 18432 + [ (s*64+lane)*8 + j ]  -> 9*64*8   = 4608
//   W1 frags: 23040 + [ (c*64+lane)*8 + j ]  -> 4*64*8   = 2048
// total 25088 ushort = 50176 B
//
// Frag element j on lane: k = 16*s + 8*(lane>>5) + j, f(=m) = 32*c + (lane&31)
// (A-operand k-map verified R2; phi-trick verified R3.)
// phi(k) = k with bits 2<->3 swapped, baked into W2/W3 k-index so the packed
// producer C-layout feeds the next layer's B operand with NO cross-lane ops.

__device__ __forceinline__ unsigned short f2b(float v) {  // RNE, prep only
  unsigned u = __builtin_bit_cast(unsigned, v);
  unsigned r = (u + 0x7FFFu + ((u >> 16) & 1u)) >> 16;
  return (unsigned short)r;
}

// pack 2 floats -> bf16x2 (round-half-up): 2 add + 1 v_perm
__device__ __forceinline__ unsigned pk2(float a, float b) {
  unsigned ua = __builtin_bit_cast(unsigned, a) + 0x8000u;
  unsigned ub = __builtin_bit_cast(unsigned, b) + 0x8000u;
  return __builtin_amdgcn_perm(ub, ua, 0x07060302u);  // {a.hi16, b.hi16}
}

__device__ __forceinline__ unsigned pkr(float a, float b) {  // relu + pack
  return pk2(fmaxf(a, 0.f), fmaxf(b, 0.f));
}

__device__ __forceinline__ f32x16 zero16() {
  f32x16 z;
#pragma unroll
  for (int i = 0; i < 16; ++i) z[i] = 0.f;
  return z;
}

// B-frag from one c-group's acc (16 floats), parity selects k-step 2c / 2c+1.
__device__ __forceinline__ i32x4 mkfrag(const f32x16& a, int parity) {
  const int b = parity * 8;
  i32x4 v;
  v.x = (int)pkr(a[b + 0], a[b + 1]);
  v.y = (int)pkr(a[b + 2], a[b + 3]);
  v.z = (int)pkr(a[b + 4], a[b + 5]);
  v.w = (int)pkr(a[b + 6], a[b + 7]);
  return v;
}

__device__ __forceinline__ int phi(int k) {  // swap bits 2 and 3
  return (k & ~12) | ((k & 4) << 1) | ((k & 8) >> 1);
}

// Element-parallel prep: one thread per blob element (25088).
__global__ __launch_bounds__(256) void prep_kernel(
    const float* __restrict__ W1, const float* __restrict__ b1,
    const float* __restrict__ W2, const float* __restrict__ b2,
    const float* __restrict__ W3, const float* __restrict__ b3,
    unsigned short* __restrict__ blob) {
  int idx = blockIdx.x * 256 + threadIdx.x;
  if (idx >= 25088) return;
  int j = idx & 7;
  float v;
  if (idx < 18432) {  // W2: chunk = (c*9+s)*64 + lane, k permuted by phi
    int chunk = idx >> 3;
    int lane = chunk & 63;
    int cs = chunk >> 6;
    int c = cs / 9, s = cs - 9 * c;
    int h = lane >> 5, f = 32 * c + (lane & 31);
    int k = 16 * s + 8 * h + j;
    v = (k < 128) ? W2[phi(k) * 128 + f] : ((k == 128) ? b2[f] : 0.f);
  } else if (idx < 23040) {  // W3 (M padded 3->32), k permuted by phi
    int r = (idx - 18432) >> 3;
    int lane = r & 63, s = r >> 6;
    int h = lane >> 5, f = lane & 31;
    int k = 16 * s + 8 * h + j;
    v = 0.f;
    if (f < 3) v = (k < 128) ? W3[phi(k) * 3 + f] : ((k == 128) ? b3[f] : 0.f);
  } else {  // W1 (K padded 5(+bias)->16), natural
    int r = (idx - 23040) >> 3;
    int lane = r & 63, c = r >> 6;
    int h = lane >> 5, f = 32 * c + (lane & 31);
    int k = 8 * h + j;
    v = (k < 5) ? W1[k * 128 + f] : ((k == 5) ? b1[f] : 0.f);
  }
  blob[idx] = f2b(v);
}

// Persistent kernel: 768 blocks (3/CU, all co-resident), each grid-strides
// over ~2.7 row-tiles. Weights staged ONCE per block via async
// global_load_lds; next-tile S/A prefetched into regs during current math.
__global__ __launch_bounds__(256, 3) void dyn_kernel(
    const float* __restrict__ S, const float* __restrict__ A,
    const unsigned short* __restrict__ blob, float* __restrict__ out) {
  __shared__ __align__(16) unsigned short lds[25088];
  const int tid = threadIdx.x;
  const int lane = tid & 63;
  const int wv = tid >> 6;
  const int h = lane >> 5;
  const int ln = lane & 31;

  {  // async stage whole frag blob (50 KB) into LDS; drained at the barrier.
    const GLOBAL_AS char* g = (const GLOBAL_AS char*)blob;
    LDS_AS char* l = (LDS_AS char*)lds;
#pragma unroll
    for (int i = 0; i < 12; ++i)
      __builtin_amdgcn_global_load_lds(
          (const GLOBAL_AS unsigned*)(g + 16 * (tid + 256 * i)),
          (LDS_AS unsigned*)(l + 16 * (tid + 256 * i)), 16, 0, 0);
    if (tid < 64)  // chunks 3072..3135
      __builtin_amdgcn_global_load_lds(
          (const GLOBAL_AS unsigned*)(g + 16 * (tid + 3072)),
          (LDS_AS unsigned*)(l + 16 * (tid + 3072)), 16, 0, 0);
  }

  const i32x4* w2p = (const i32x4*)lds;            // (c*9+s)*64 + lane
  const i32x4* w3p = (const i32x4*)(lds + 18432);  // s*64 + lane
  const i32x4* w1p = (const i32x4*)(lds + 23040);  // c*64 + lane

  i32x4 bias_frag;  // B[k=128][*] = 1.0 on h=0 lanes, rest 0
  bias_frag.x = h ? 0 : 0x3F80;
  bias_frag.y = 0; bias_frag.z = 0; bias_frag.w = 0;

  // first tile's inputs (overlap with the weight DMA)
  int tile = blockIdx.x;
  int row = tile * 256 + wv * 64 + lane;
  float sx = S[row * 3 + 0], sy = S[row * 3 + 1], sz = S[row * 3 + 2];
  float2 av = ((const float2*)A)[row];
  float ax = av.x, ay = av.y;

  __syncthreads();  // drains the weight DMA

  for (;;) {
    const int ntile = tile + NBLK;
    const bool more = ntile < NTILES;
    // ---- prefetch next tile's inputs (guarded; used next iteration) ----
    const int prow = (more ? ntile : tile) * 256 + wv * 64 + lane;
    const float nsx = S[prow * 3 + 0], nsy = S[prow * 3 + 1], nsz = S[prow * 3 + 2];
    const float2 nav = ((const float2*)A)[prow];

    // ---- reward, fp32 ----
    {
      float quad = 30.f * ((sx - ax) * (sx - ax) + (sy - ay) * (sy - ay));
      const float OX[6] = {0.f, 0.f, 0.f, 0.f, 0.f, -0.8f};
      const float OY[6] = {0.f, 0.2f, 0.4f, 0.6f, 0.8f, -0.8f};
      const float C2 = 20.609622817083824f;  // log2(e)/(2*VAR)
      float gs = 0.f;
#pragma unroll
      for (int i = 0; i < 6; ++i) {
        float dx = sx - OX[i], dy = sy - OY[i];
        gs += __builtin_amdgcn_exp2f(-(dx * dx + dy * dy) * C2);
      }
      const float IB = 801.5624162594774f;  // log2(e)/(2*SIG^2)
      float e1 = sx + 1.5f, e2 = sx - 1.5f, e3 = sy - 1.0f, e4 = sy + 1.0f;
      float bnd = __builtin_amdgcn_exp2f(-e1 * e1 * IB) +
                  __builtin_amdgcn_exp2f(-e2 * e2 * IB) +
                  __builtin_amdgcn_exp2f(-e3 * e3 * IB) +
                  __builtin_amdgcn_exp2f(-e4 * e4 * IB);
      out[3 * B_N + row] =
          -(quad + 454.72840883398667f * gs + 132.98076013381091f * bnd);
    }

    // x frags for both 32-sample halves (t=1 data via lane-pair shuffle)
    const float u0 = __shfl_xor(sx, 32, 64), u1 = __shfl_xor(sy, 32, 64);
    const float u2 = __shfl_xor(sz, 32, 64), u3 = __shfl_xor(ax, 32, 64);
    const float u4 = __shfl_xor(ay, 32, 64);

    i32x4 xf[2];
    xf[0].x = h ? 0 : (int)pk2(sx, sy);
    xf[0].y = h ? 0 : (int)pk2(sz, ax);
    xf[0].z = h ? 0 : (int)pk2(ay, 1.0f);
    xf[0].w = 0;
    xf[1].x = h ? 0 : (int)pk2(u0, u1);
    xf[1].y = h ? 0 : (int)pk2(u2, u3);
    xf[1].z = h ? 0 : (int)pk2(u4, 1.0f);
    xf[1].w = 0;

    // ---- L1 + pack (per half; one acc1 set live at a time) ----
    i32x4 bf2[2][8];
#pragma unroll
    for (int t = 0; t < 2; ++t) {
      bf16x8 xb = __builtin_bit_cast(bf16x8, xf[t]);
      f32x16 acc1[4];
#pragma unroll
      for (int c = 0; c < 4; ++c)
        acc1[c] = __builtin_amdgcn_mfma_f32_32x32x16_bf16(
            __builtin_bit_cast(bf16x8, w1p[c * 64 + lane]), xb, zero16(), 0, 0, 0);
#pragma unroll
      for (int s = 0; s < 8; ++s) bf2[t][s] = mkfrag(acc1[s >> 1], s & 1);
    }

    // ---- L2 in 4 c-groups, each feeding L3 immediately (caps live regs) ----
    f32x16 acc3[2];
    acc3[0] = zero16();
    acc3[1] = zero16();
#pragma unroll
    for (int g = 0; g < 4; ++g) {
      f32x16 a2g[2];
      a2g[0] = zero16();
      a2g[1] = zero16();
#pragma unroll
      for (int s = 0; s < 9; ++s) {
        bf16x8 aa = __builtin_bit_cast(bf16x8, w2p[(g * 9 + s) * 64 + lane]);
        bf16x8 b0 = __builtin_bit_cast(bf16x8, s < 8 ? bf2[0][s] : bias_frag);
        bf16x8 b1 = __builtin_bit_cast(bf16x8, s < 8 ? bf2[1][s] : bias_frag);
        a2g[0] = __builtin_amdgcn_mfma_f32_32x32x16_bf16(aa, b0, a2g[0], 0, 0, 0);
        a2g[1] = __builtin_amdgcn_mfma_f32_32x32x16_bf16(aa, b1, a2g[1], 0, 0, 0);
      }
#pragma unroll
      for (int p = 0; p < 2; ++p) {
        bf16x8 w3f = __builtin_bit_cast(bf16x8, w3p[(2 * g + p) * 64 + lane]);
#pragma unroll
        for (int t = 0; t < 2; ++t) {
          i32x4 fr = mkfrag(a2g[t], p);
          acc3[t] = __builtin_amdgcn_mfma_f32_32x32x16_bf16(
              w3f, __builtin_bit_cast(bf16x8, fr), acc3[t], 0, 0, 0);
        }
      }
    }
    {  // L3 bias k-step (s=8)
      bf16x8 w3f = __builtin_bit_cast(bf16x8, w3p[8 * 64 + lane]);
      bf16x8 bb = __builtin_bit_cast(bf16x8, bias_frag);
      acc3[0] = __builtin_amdgcn_mfma_f32_32x32x16_bf16(w3f, bb, acc3[0], 0, 0, 0);
      acc3[1] = __builtin_amdgcn_mfma_f32_32x32x16_bf16(w3f, bb, acc3[1], 0, 0, 0);
    }

    // ---- store s_next: C-layout h=0 lanes, regs 0..2 ----
    if (h == 0) {
      const int rbase = tile * 256 + wv * 64;
#pragma unroll
      for (int t = 0; t < 2; ++t) {
        int r = rbase + 32 * t + ln;
        float* p = out + r * 3;
        p[0] = acc3[t][0];
        p[1] = acc3[t][1];
        p[2] = acc3[t][2];
      }
    }

    if (!more) break;
    tile = ntile;
    row = prow;
    sx = nsx; sy = nsy; sz = nsz;
    ax = nav.x; ay = nav.y;
  }
}

extern "C" void kernel_launch(void* const* d_in, const int* in_sizes, int n_in,
                              void* d_out, int out_size, void* d_ws, size_t ws_size,
                              hipStream_t stream) {
  const float* S = (const float*)d_in[0];
  const float* A = (const float*)d_in[1];
  const float* W1 = (const float*)d_in[2];
  const float* b1 = (const float*)d_in[3];
  const float* W2 = (const float*)d_in[4];
  const float* b2 = (const float*)d_in[5];
  const float* W3 = (const float*)d_in[6];
  const float* b3 = (const float*)d_in[7];
  unsigned short* blob = (unsigned short*)d_ws;
  float* out = (float*)d_out;

  prep_kernel<<<dim3(98), dim3(256), 0, stream>>>(W1, b1, W2, b2, W3, b3, blob);
  dyn_kernel<<<dim3(NBLK), dim3(256), 0, stream>>>(S, A, blob, out);
}

// Round 8
// 125.611 us; speedup vs baseline: 1.2710x; 1.2710x over previous
//
#include <hip/hip_runtime.h>

#define B_N 524288
#define NTILES 2048   // 256 rows per tile
#define NBLK 512      // 2 blocks/CU * 256 CU co-resident; 4 tiles per block

typedef __attribute__((ext_vector_type(8))) short bf16x8;
typedef __attribute__((ext_vector_type(16))) float f32x16;
typedef __attribute__((ext_vector_type(4))) int i32x4;

#define GLOBAL_AS __attribute__((address_space(1)))
#define LDS_AS __attribute__((address_space(3)))

// ws blob layout (ushort units):
//   W2 frags: [ ((c*9+s)*64 + lane)*8 + j ]  -> 4*9*64*8 = 18432
//   W3 frags: 18432 + [ (s*64+lane)*8 + j ]  -> 9*64*8   = 4608
//   W1 frags: 23040 + [ (c*64+lane)*8 + j ]  -> 4*64*8   = 2048
// total 25088 ushort = 50176 B
//
// Frag element j on lane: k = 16*s + 8*(lane>>5) + j, f(=m) = 32*c + (lane&31)
// (A-operand k-map verified R2; phi-trick verified R3.)
// phi(k) = k with bits 2<->3 swapped, baked into W2/W3 k-index so the packed
// producer C-layout feeds the next layer's B operand with NO cross-lane ops.
//
// R7 lesson: __launch_bounds__(256,3) caps unified VGPR+AGPR at ~170/wave ->
// the persistent loop's extra live state spilled ~280 MB of scratch traffic.
// (256,2) gives a 256-reg budget; working set ~190 fits. NBLK=512 keeps all
// blocks co-resident at 2/CU.

__device__ __forceinline__ unsigned short f2b(float v) {  // RNE, prep only
  unsigned u = __builtin_bit_cast(unsigned, v);
  unsigned r = (u + 0x7FFFu + ((u >> 16) & 1u)) >> 16;
  return (unsigned short)r;
}

// pack 2 floats -> bf16x2 (round-half-up): 2 add + 1 v_perm
__device__ __forceinline__ unsigned pk2(float a, float b) {
  unsigned ua = __builtin_bit_cast(unsigned, a) + 0x8000u;
  unsigned ub = __builtin_bit_cast(unsigned, b) + 0x8000u;
  return __builtin_amdgcn_perm(ub, ua, 0x07060302u);  // {a.hi16, b.hi16}
}

__device__ __forceinline__ unsigned pkr(float a, float b) {  // relu + pack
  return pk2(fmaxf(a, 0.f), fmaxf(b, 0.f));
}

__device__ __forceinline__ f32x16 zero16() {
  f32x16 z;
#pragma unroll
  for (int i = 0; i < 16; ++i) z[i] = 0.f;
  return z;
}

// B-frag from one c-group's acc (16 floats), parity selects k-step 2c / 2c+1.
__device__ __forceinline__ i32x4 mkfrag(const f32x16& a, int parity) {
  const int b = parity * 8;
  i32x4 v;
  v.x = (int)pkr(a[b + 0], a[b + 1]);
  v.y = (int)pkr(a[b + 2], a[b + 3]);
  v.z = (int)pkr(a[b + 4], a[b + 5]);
  v.w = (int)pkr(a[b + 6], a[b + 7]);
  return v;
}

__device__ __forceinline__ int phi(int k) {  // swap bits 2 and 3
  return (k & ~12) | ((k & 4) << 1) | ((k & 8) >> 1);
}

// Element-parallel prep: one thread per blob element (25088).
__global__ __launch_bounds__(256) void prep_kernel(
    const float* __restrict__ W1, const float* __restrict__ b1,
    const float* __restrict__ W2, const float* __restrict__ b2,
    const float* __restrict__ W3, const float* __restrict__ b3,
    unsigned short* __restrict__ blob) {
  int idx = blockIdx.x * 256 + threadIdx.x;
  if (idx >= 25088) return;
  int j = idx & 7;
  float v;
  if (idx < 18432) {  // W2: chunk = (c*9+s)*64 + lane, k permuted by phi
    int chunk = idx >> 3;
    int lane = chunk & 63;
    int cs = chunk >> 6;
    int c = cs / 9, s = cs - 9 * c;
    int h = lane >> 5, f = 32 * c + (lane & 31);
    int k = 16 * s + 8 * h + j;
    v = (k < 128) ? W2[phi(k) * 128 + f] : ((k == 128) ? b2[f] : 0.f);
  } else if (idx < 23040) {  // W3 (M padded 3->32), k permuted by phi
    int r = (idx - 18432) >> 3;
    int lane = r & 63, s = r >> 6;
    int h = lane >> 5, f = lane & 31;
    int k = 16 * s + 8 * h + j;
    v = 0.f;
    if (f < 3) v = (k < 128) ? W3[phi(k) * 3 + f] : ((k == 128) ? b3[f] : 0.f);
  } else {  // W1 (K padded 5(+bias)->16), natural
    int r = (idx - 23040) >> 3;
    int lane = r & 63, c = r >> 6;
    int h = lane >> 5, f = 32 * c + (lane & 31);
    int k = 8 * h + j;
    v = (k < 5) ? W1[k * 128 + f] : ((k == 5) ? b1[f] : 0.f);
  }
  blob[idx] = f2b(v);
}

// Persistent kernel: 512 blocks (2/CU, all co-resident), 4 tiles per block.
// Weights staged ONCE per block via async global_load_lds; next-tile S/A
// prefetched into regs during current tile's math.
__global__ __launch_bounds__(256, 2) void dyn_kernel(
    const float* __restrict__ S, const float* __restrict__ A,
    const unsigned short* __restrict__ blob, float* __restrict__ out) {
  __shared__ __align__(16) unsigned short lds[25088];
  const int tid = threadIdx.x;
  const int lane = tid & 63;
  const int wv = tid >> 6;
  const int h = lane >> 5;
  const int ln = lane & 31;

  {  // async stage whole frag blob (50 KB) into LDS; drained at the barrier.
    const GLOBAL_AS char* g = (const GLOBAL_AS char*)blob;
    LDS_AS char* l = (LDS_AS char*)lds;
#pragma unroll
    for (int i = 0; i < 12; ++i)
      __builtin_amdgcn_global_load_lds(
          (const GLOBAL_AS unsigned*)(g + 16 * (tid + 256 * i)),
          (LDS_AS unsigned*)(l + 16 * (tid + 256 * i)), 16, 0, 0);
    if (tid < 64)  // chunks 3072..3135
      __builtin_amdgcn_global_load_lds(
          (const GLOBAL_AS unsigned*)(g + 16 * (tid + 3072)),
          (LDS_AS unsigned*)(l + 16 * (tid + 3072)), 16, 0, 0);
  }

  const i32x4* w2p = (const i32x4*)lds;            // (c*9+s)*64 + lane
  const i32x4* w3p = (const i32x4*)(lds + 18432);  // s*64 + lane
  const i32x4* w1p = (const i32x4*)(lds + 23040);  // c*64 + lane

  i32x4 bias_frag;  // B[k=128][*] = 1.0 on h=0 lanes, rest 0
  bias_frag.x = h ? 0 : 0x3F80;
  bias_frag.y = 0; bias_frag.z = 0; bias_frag.w = 0;

  // first tile's inputs (overlap with the weight DMA)
  int tile = blockIdx.x;
  int row = tile * 256 + wv * 64 + lane;
  float sx = S[row * 3 + 0], sy = S[row * 3 + 1], sz = S[row * 3 + 2];
  float2 av = ((const float2*)A)[row];
  float ax = av.x, ay = av.y;

  __syncthreads();  // drains the weight DMA

  for (;;) {
    const int ntile = tile + NBLK;
    const bool more = ntile < NTILES;
    // ---- prefetch next tile's inputs (guarded; used next iteration) ----
    const int prow = (more ? ntile : tile) * 256 + wv * 64 + lane;
    const float nsx = S[prow * 3 + 0], nsy = S[prow * 3 + 1], nsz = S[prow * 3 + 2];
    const float2 nav = ((const float2*)A)[prow];

    // ---- reward, fp32 ----
    {
      float quad = 30.f * ((sx - ax) * (sx - ax) + (sy - ay) * (sy - ay));
      const float OX[6] = {0.f, 0.f, 0.f, 0.f, 0.f, -0.8f};
      const float OY[6] = {0.f, 0.2f, 0.4f, 0.6f, 0.8f, -0.8f};
      const float C2 = 20.609622817083824f;  // log2(e)/(2*VAR)
      float gs = 0.f;
#pragma unroll
      for (int i = 0; i < 6; ++i) {
        float dx = sx - OX[i], dy = sy - OY[i];
        gs += __builtin_amdgcn_exp2f(-(dx * dx + dy * dy) * C2);
      }
      const float IB = 801.5624162594774f;  // log2(e)/(2*SIG^2)
      float e1 = sx + 1.5f, e2 = sx - 1.5f, e3 = sy - 1.0f, e4 = sy + 1.0f;
      float bnd = __builtin_amdgcn_exp2f(-e1 * e1 * IB) +
                  __builtin_amdgcn_exp2f(-e2 * e2 * IB) +
                  __builtin_amdgcn_exp2f(-e3 * e3 * IB) +
                  __builtin_amdgcn_exp2f(-e4 * e4 * IB);
      out[3 * B_N + row] =
          -(quad + 454.72840883398667f * gs + 132.98076013381091f * bnd);
    }

    // x frags for both 32-sample halves (t=1 data via lane-pair shuffle)
    const float u0 = __shfl_xor(sx, 32, 64), u1 = __shfl_xor(sy, 32, 64);
    const float u2 = __shfl_xor(sz, 32, 64), u3 = __shfl_xor(ax, 32, 64);
    const float u4 = __shfl_xor(ay, 32, 64);

    i32x4 xf[2];
    xf[0].x = h ? 0 : (int)pk2(sx, sy);
    xf[0].y = h ? 0 : (int)pk2(sz, ax);
    xf[0].z = h ? 0 : (int)pk2(ay, 1.0f);
    xf[0].w = 0;
    xf[1].x = h ? 0 : (int)pk2(u0, u1);
    xf[1].y = h ? 0 : (int)pk2(u2, u3);
    xf[1].z = h ? 0 : (int)pk2(u4, 1.0f);
    xf[1].w = 0;

    // ---- L1 + pack (per half; one acc1 set live at a time) ----
    i32x4 bf2[2][8];
#pragma unroll
    for (int t = 0; t < 2; ++t) {
      bf16x8 xb = __builtin_bit_cast(bf16x8, xf[t]);
      f32x16 acc1[4];
#pragma unroll
      for (int c = 0; c < 4; ++c)
        acc1[c] = __builtin_amdgcn_mfma_f32_32x32x16_bf16(
            __builtin_bit_cast(bf16x8, w1p[c * 64 + lane]), xb, zero16(), 0, 0, 0);
#pragma unroll
      for (int s = 0; s < 8; ++s) bf2[t][s] = mkfrag(acc1[s >> 1], s & 1);
    }

    // ---- L2 in 4 c-groups, each feeding L3 immediately (caps live regs) ----
    f32x16 acc3[2];
    acc3[0] = zero16();
    acc3[1] = zero16();
#pragma unroll
    for (int g = 0; g < 4; ++g) {
      f32x16 a2g[2];
      a2g[0] = zero16();
      a2g[1] = zero16();
#pragma unroll
      for (int s = 0; s < 9; ++s) {
        bf16x8 aa = __builtin_bit_cast(bf16x8, w2p[(g * 9 + s) * 64 + lane]);
        bf16x8 b0 = __builtin_bit_cast(bf16x8, s < 8 ? bf2[0][s] : bias_frag);
        bf16x8 b1 = __builtin_bit_cast(bf16x8, s < 8 ? bf2[1][s] : bias_frag);
        a2g[0] = __builtin_amdgcn_mfma_f32_32x32x16_bf16(aa, b0, a2g[0], 0, 0, 0);
        a2g[1] = __builtin_amdgcn_mfma_f32_32x32x16_bf16(aa, b1, a2g[1], 0, 0, 0);
      }
#pragma unroll
      for (int p = 0; p < 2; ++p) {
        bf16x8 w3f = __builtin_bit_cast(bf16x8, w3p[(2 * g + p) * 64 + lane]);
#pragma unroll
        for (int t = 0; t < 2; ++t) {
          i32x4 fr = mkfrag(a2g[t], p);
          acc3[t] = __builtin_amdgcn_mfma_f32_32x32x16_bf16(
              w3f, __builtin_bit_cast(bf16x8, fr), acc3[t], 0, 0, 0);
        }
      }
    }
    {  // L3 bias k-step (s=8)
      bf16x8 w3f = __builtin_bit_cast(bf16x8, w3p[8 * 64 + lane]);
      bf16x8 bb = __builtin_bit_cast(bf16x8, bias_frag);
      acc3[0] = __builtin_amdgcn_mfma_f32_32x32x16_bf16(w3f, bb, acc3[0], 0, 0, 0);
      acc3[1] = __builtin_amdgcn_mfma_f32_32x32x16_bf16(w3f, bb, acc3[1], 0, 0, 0);
    }

    // ---- store s_next: C-layout h=0 lanes, regs 0..2 ----
    if (h == 0) {
      const int rbase = tile * 256 + wv * 64;
#pragma unroll
      for (int t = 0; t < 2; ++t) {
        int r = rbase + 32 * t + ln;
        float* p = out + r * 3;
        p[0] = acc3[t][0];
        p[1] = acc3[t][1];
        p[2] = acc3[t][2];
      }
    }

    if (!more) break;
    tile = ntile;
    row = prow;
    sx = nsx; sy = nsy; sz = nsz;
    ax = nav.x; ay = nav.y;
  }
}

extern "C" void kernel_launch(void* const* d_in, const int* in_sizes, int n_in,
                              void* d_out, int out_size, void* d_ws, size_t ws_size,
                              hipStream_t stream) {
  const float* S = (const float*)d_in[0];
  const float* A = (const float*)d_in[1];
  const float* W1 = (const float*)d_in[2];
  const float* b1 = (const float*)d_in[3];
  const float* W2 = (const float*)d_in[4];
  const float* b2 = (const float*)d_in[5];
  const float* W3 = (const float*)d_in[6];
  const float* b3 = (const float*)d_in[7];
  unsigned short* blob = (unsigned short*)d_ws;
  float* out = (float*)d_out;

  prep_kernel<<<dim3(98), dim3(256), 0, stream>>>(W1, b1, W2, b2, W3, b3, blob);
  dyn_kernel<<<dim3(NBLK), dim3(256), 0, stream>>>(S, A, blob, out);
}

// Round 9
// 101.600 us; speedup vs baseline: 1.5713x; 1.2363x over previous
//
#include <hip/hip_runtime.h>

#define B_N 524288

typedef __attribute__((ext_vector_type(8))) short bf16x8;
typedef __attribute__((ext_vector_type(16))) float f32x16;
typedef __attribute__((ext_vector_type(4))) int i32x4;

#define GLOBAL_AS __attribute__((address_space(1)))
#define LDS_AS __attribute__((address_space(3)))

// ws blob layout (ushort units):
//   W2 frags: [ ((c*9+s)*64 + lane)*8 + j ]  -> 4*9*64*8 = 18432
//   W3 frags: 18432 + [ (s*64+lane)*8 + j ]  -> 9*64*8   = 4608
//   W1 frags: 23040 + [ (c*64+lane)*8 + j ]  -> 4*64*8   = 2048
// total 25088 ushort = 50176 B
//
// Frag element j on lane: k = 16*s + 8*(lane>>5) + j, f(=m) = 32*c + (lane&31)
// (A-operand k-map verified R2; phi-trick verified R3.)
// phi(k) = k with bits 2<->3 swapped, baked into W2/W3 k-index so the packed
// producer C-layout feeds the next layer's B operand with NO cross-lane ops.
//
// R7/R8 lesson: ANY __launch_bounds__ min-waves clamp (170- or 256-reg
// budget) made the allocator spill 50-280 MB of scratch traffic. The only
// measured-clean config is free allocation (R2: VGPR 88, FETCH 5.4 MB).
// LDS (50 KB) caps residency at 3 blocks/CU regardless, so the clamp bought
// nothing. Non-persistent grid; no clamp.

__device__ __forceinline__ unsigned short f2b(float v) {  // RNE, prep only
  unsigned u = __builtin_bit_cast(unsigned, v);
  unsigned r = (u + 0x7FFFu + ((u >> 16) & 1u)) >> 16;
  return (unsigned short)r;
}

// pack 2 floats -> bf16x2 (round-half-up): 2 add + 1 v_perm
__device__ __forceinline__ unsigned pk2(float a, float b) {
  unsigned ua = __builtin_bit_cast(unsigned, a) + 0x8000u;
  unsigned ub = __builtin_bit_cast(unsigned, b) + 0x8000u;
  return __builtin_amdgcn_perm(ub, ua, 0x07060302u);  // {a.hi16, b.hi16}
}

__device__ __forceinline__ unsigned pkr(float a, float b) {  // relu + pack
  return pk2(fmaxf(a, 0.f), fmaxf(b, 0.f));
}

__device__ __forceinline__ f32x16 zero16() {
  f32x16 z;
#pragma unroll
  for (int i = 0; i < 16; ++i) z[i] = 0.f;
  return z;
}

// B-frag from one c-group's acc (16 floats), parity selects k-step 2c / 2c+1.
__device__ __forceinline__ i32x4 mkfrag(const f32x16& a, int parity) {
  const int b = parity * 8;
  i32x4 v;
  v.x = (int)pkr(a[b + 0], a[b + 1]);
  v.y = (int)pkr(a[b + 2], a[b + 3]);
  v.z = (int)pkr(a[b + 4], a[b + 5]);
  v.w = (int)pkr(a[b + 6], a[b + 7]);
  return v;
}

__device__ __forceinline__ int phi(int k) {  // swap bits 2 and 3
  return (k & ~12) | ((k & 4) << 1) | ((k & 8) >> 1);
}

// Element-parallel prep: one thread per blob element (25088).
__global__ __launch_bounds__(256) void prep_kernel(
    const float* __restrict__ W1, const float* __restrict__ b1,
    const float* __restrict__ W2, const float* __restrict__ b2,
    const float* __restrict__ W3, const float* __restrict__ b3,
    unsigned short* __restrict__ blob) {
  int idx = blockIdx.x * 256 + threadIdx.x;
  if (idx >= 25088) return;
  int j = idx & 7;
  float v;
  if (idx < 18432) {  // W2: chunk = (c*9+s)*64 + lane, k permuted by phi
    int chunk = idx >> 3;
    int lane = chunk & 63;
    int cs = chunk >> 6;
    int c = cs / 9, s = cs - 9 * c;
    int h = lane >> 5, f = 32 * c + (lane & 31);
    int k = 16 * s + 8 * h + j;
    v = (k < 128) ? W2[phi(k) * 128 + f] : ((k == 128) ? b2[f] : 0.f);
  } else if (idx < 23040) {  // W3 (M padded 3->32), k permuted by phi
    int r = (idx - 18432) >> 3;
    int lane = r & 63, s = r >> 6;
    int h = lane >> 5, f = lane & 31;
    int k = 16 * s + 8 * h + j;
    v = 0.f;
    if (f < 3) v = (k < 128) ? W3[phi(k) * 3 + f] : ((k == 128) ? b3[f] : 0.f);
  } else {  // W1 (K padded 5(+bias)->16), natural
    int r = (idx - 23040) >> 3;
    int lane = r & 63, c = r >> 6;
    int h = lane >> 5, f = 32 * c + (lane & 31);
    int k = 8 * h + j;
    v = (k < 5) ? W1[k * 128 + f] : ((k == 5) ? b1[f] : 0.f);
  }
  blob[idx] = f2b(v);
}

// Non-persistent: 2048 blocks of 256 (one 256-row tile each), free register
// allocation (no min-waves clamp -> no spills). Staging via async
// global_load_lds width=16, overlapped with the fp32 reward.
__global__ __launch_bounds__(256) void dyn_kernel(
    const float* __restrict__ S, const float* __restrict__ A,
    const unsigned short* __restrict__ blob, float* __restrict__ out) {
  __shared__ __align__(16) unsigned short lds[25088];
  const int tid = threadIdx.x;
  const int lane = tid & 63;
  const int wv = tid >> 6;
  const int h = lane >> 5;
  const int ln = lane & 31;

  {  // async stage whole frag blob (50 KB) into LDS; drained at the barrier.
    const GLOBAL_AS char* g = (const GLOBAL_AS char*)blob;
    LDS_AS char* l = (LDS_AS char*)lds;
#pragma unroll
    for (int i = 0; i < 12; ++i)
      __builtin_amdgcn_global_load_lds(
          (const GLOBAL_AS unsigned*)(g + 16 * (tid + 256 * i)),
          (LDS_AS unsigned*)(l + 16 * (tid + 256 * i)), 16, 0, 0);
    if (tid < 64)  // chunks 3072..3135
      __builtin_amdgcn_global_load_lds(
          (const GLOBAL_AS unsigned*)(g + 16 * (tid + 3072)),
          (LDS_AS unsigned*)(l + 16 * (tid + 3072)), 16, 0, 0);
  }

  const int r0 = blockIdx.x * 256 + wv * 64;  // wave covers rows [r0, r0+64)
  const int row = r0 + lane;

  const float sx = S[row * 3 + 0], sy = S[row * 3 + 1], sz = S[row * 3 + 2];
  const float2 av = ((const float2*)A)[row];
  const float ax = av.x, ay = av.y;

  // ---- reward, fp32, overlapped with the staging DMA ----
  {
    float quad = 30.f * ((sx - ax) * (sx - ax) + (sy - ay) * (sy - ay));
    const float OX[6] = {0.f, 0.f, 0.f, 0.f, 0.f, -0.8f};
    const float OY[6] = {0.f, 0.2f, 0.4f, 0.6f, 0.8f, -0.8f};
    const float C2 = 20.609622817083824f;  // log2(e)/(2*VAR)
    float gs = 0.f;
#pragma unroll
    for (int i = 0; i < 6; ++i) {
      float dx = sx - OX[i], dy = sy - OY[i];
      gs += __builtin_amdgcn_exp2f(-(dx * dx + dy * dy) * C2);
    }
    const float IB = 801.5624162594774f;  // log2(e)/(2*SIG^2)
    float e1 = sx + 1.5f, e2 = sx - 1.5f, e3 = sy - 1.0f, e4 = sy + 1.0f;
    float bnd = __builtin_amdgcn_exp2f(-e1 * e1 * IB) +
                __builtin_amdgcn_exp2f(-e2 * e2 * IB) +
                __builtin_amdgcn_exp2f(-e3 * e3 * IB) +
                __builtin_amdgcn_exp2f(-e4 * e4 * IB);
    out[3 * B_N + row] =
        -(quad + 454.72840883398667f * gs + 132.98076013381091f * bnd);
  }

  __syncthreads();  // drains the weight DMA

  const i32x4* w2p = (const i32x4*)lds;            // (c*9+s)*64 + lane
  const i32x4* w3p = (const i32x4*)(lds + 18432);  // s*64 + lane
  const i32x4* w1p = (const i32x4*)(lds + 23040);  // c*64 + lane

  // x frags for both 32-sample halves (t=1 data via lane-pair shuffle)
  const float u0 = __shfl_xor(sx, 32, 64), u1 = __shfl_xor(sy, 32, 64);
  const float u2 = __shfl_xor(sz, 32, 64), u3 = __shfl_xor(ax, 32, 64);
  const float u4 = __shfl_xor(ay, 32, 64);

  i32x4 xf[2];
  xf[0].x = h ? 0 : (int)pk2(sx, sy);
  xf[0].y = h ? 0 : (int)pk2(sz, ax);
  xf[0].z = h ? 0 : (int)pk2(ay, 1.0f);
  xf[0].w = 0;
  xf[1].x = h ? 0 : (int)pk2(u0, u1);
  xf[1].y = h ? 0 : (int)pk2(u2, u3);
  xf[1].z = h ? 0 : (int)pk2(u4, 1.0f);
  xf[1].w = 0;

  i32x4 bias_frag;  // B[k=128][*] = 1.0 on h=0 lanes, rest 0
  bias_frag.x = h ? 0 : 0x3F80;
  bias_frag.y = 0; bias_frag.z = 0; bias_frag.w = 0;

  // ---- L1 + pack (per half; one acc1 set live at a time) ----
  i32x4 bf2[2][8];
#pragma unroll
  for (int t = 0; t < 2; ++t) {
    bf16x8 xb = __builtin_bit_cast(bf16x8, xf[t]);
    f32x16 acc1[4];
#pragma unroll
    for (int c = 0; c < 4; ++c)
      acc1[c] = __builtin_amdgcn_mfma_f32_32x32x16_bf16(
          __builtin_bit_cast(bf16x8, w1p[c * 64 + lane]), xb, zero16(), 0, 0, 0);
#pragma unroll
    for (int s = 0; s < 8; ++s) bf2[t][s] = mkfrag(acc1[s >> 1], s & 1);
  }

  // ---- L2 in 4 c-groups, each feeding L3 immediately (caps live regs) ----
  f32x16 acc3[2];
  acc3[0] = zero16();
  acc3[1] = zero16();
#pragma unroll
  for (int g = 0; g < 4; ++g) {
    f32x16 a2g[2];
    a2g[0] = zero16();
    a2g[1] = zero16();
#pragma unroll
    for (int s = 0; s < 9; ++s) {
      bf16x8 aa = __builtin_bit_cast(bf16x8, w2p[(g * 9 + s) * 64 + lane]);
      bf16x8 b0 = __builtin_bit_cast(bf16x8, s < 8 ? bf2[0][s] : bias_frag);
      bf16x8 b1 = __builtin_bit_cast(bf16x8, s < 8 ? bf2[1][s] : bias_frag);
      a2g[0] = __builtin_amdgcn_mfma_f32_32x32x16_bf16(aa, b0, a2g[0], 0, 0, 0);
      a2g[1] = __builtin_amdgcn_mfma_f32_32x32x16_bf16(aa, b1, a2g[1], 0, 0, 0);
    }
#pragma unroll
    for (int p = 0; p < 2; ++p) {
      bf16x8 w3f = __builtin_bit_cast(bf16x8, w3p[(2 * g + p) * 64 + lane]);
#pragma unroll
      for (int t = 0; t < 2; ++t) {
        i32x4 fr = mkfrag(a2g[t], p);
        acc3[t] = __builtin_amdgcn_mfma_f32_32x32x16_bf16(
            w3f, __builtin_bit_cast(bf16x8, fr), acc3[t], 0, 0, 0);
      }
    }
  }
  {  // L3 bias k-step (s=8)
    bf16x8 w3f = __builtin_bit_cast(bf16x8, w3p[8 * 64 + lane]);
    bf16x8 bb = __builtin_bit_cast(bf16x8, bias_frag);
    acc3[0] = __builtin_amdgcn_mfma_f32_32x32x16_bf16(w3f, bb, acc3[0], 0, 0, 0);
    acc3[1] = __builtin_amdgcn_mfma_f32_32x32x16_bf16(w3f, bb, acc3[1], 0, 0, 0);
  }

  // ---- store s_next: C-layout h=0 lanes, regs 0..2 ----
  if (h == 0) {
#pragma unroll
    for (int t = 0; t < 2; ++t) {
      int r = r0 + 32 * t + ln;
      float* p = out + r * 3;
      p[0] = acc3[t][0];
      p[1] = acc3[t][1];
      p[2] = acc3[t][2];
    }
  }
}

extern "C" void kernel_launch(void* const* d_in, const int* in_sizes, int n_in,
                              void* d_out, int out_size, void* d_ws, size_t ws_size,
                              hipStream_t stream) {
  const float* S = (const float*)d_in[0];
  const float* A = (const float*)d_in[1];
  const float* W1 = (const float*)d_in[2];
  const float* b1 = (const float*)d_in[3];
  const float* W2 = (const float*)d_in[4];
  const float* b2 = (const float*)d_in[5];
  const float* W3 = (const float*)d_in[6];
  const float* b3 = (const float*)d_in[7];
  unsigned short* blob = (unsigned short*)d_ws;
  float* out = (float*)d_out;

  prep_kernel<<<dim3(98), dim3(256), 0, stream>>>(W1, b1, W2, b2, W3, b3, blob);
  dyn_kernel<<<dim3(B_N / 256), dim3(256), 0, stream>>>(S, A, blob, out);
}

// Round 10
// 96.204 us; speedup vs baseline: 1.6594x; 1.0561x over previous
//
#include <hip/hip_runtime.h>

#define B_N 524288

typedef __attribute__((ext_vector_type(8))) short bf16x8;
typedef __attribute__((ext_vector_type(16))) float f32x16;
typedef __attribute__((ext_vector_type(4))) int i32x4;

#define GLOBAL_AS __attribute__((address_space(1)))
#define LDS_AS __attribute__((address_space(3)))

// ws blob layout (ushort units):
//   W2 frags: [ ((c*9+s)*64 + lane)*8 + j ]  -> 4*9*64*8 = 18432
//   W3 frags: 18432 + [ (s*64+lane)*8 + j ]  -> 9*64*8   = 4608
//   W1 frags: 23040 + [ (c*64+lane)*8 + j ]  -> 4*64*8   = 2048
// total 25088 ushort = 50176 B
//
// Frag element j on lane: k = 16*s + 8*(lane>>5) + j, f(=m) = 32*c + (lane&31)
// (A-operand k-map verified R2; phi-trick verified R3.)
// phi(k) = k with bits 2<->3 swapped, baked into W2/W3 k-index so the packed
// producer C-layout feeds the next layer's B operand with NO cross-lane ops.
//
// Config history: non-persistent + (256,3) = best measured (R6, 98.3);
// persistent bodies spilled under any clamp (R7/R8); free alloc = 101.6 (R9).
// This round: (256,3) + shared-ZERO accumulator seeding (kills ~270
// v_accvgpr/zero writes) + drop lane-masking that A's zero k-slots make
// redundant (A pad is exactly +0; B garbage there is finite -> 0*finite=0).

__device__ __forceinline__ unsigned short f2b(float v) {  // RNE, prep only
  unsigned u = __builtin_bit_cast(unsigned, v);
  unsigned r = (u + 0x7FFFu + ((u >> 16) & 1u)) >> 16;
  return (unsigned short)r;
}

// pack 2 floats -> bf16x2 (round-half-up): 2 add + 1 v_perm
__device__ __forceinline__ unsigned pk2(float a, float b) {
  unsigned ua = __builtin_bit_cast(unsigned, a) + 0x8000u;
  unsigned ub = __builtin_bit_cast(unsigned, b) + 0x8000u;
  return __builtin_amdgcn_perm(ub, ua, 0x07060302u);  // {a.hi16, b.hi16}
}

__device__ __forceinline__ unsigned pkr(float a, float b) {  // relu + pack
  return pk2(fmaxf(a, 0.f), fmaxf(b, 0.f));
}

__device__ __forceinline__ f32x16 zero16() {
  f32x16 z;
#pragma unroll
  for (int i = 0; i < 16; ++i) z[i] = 0.f;
  return z;
}

// B-frag from one c-group's acc (16 floats), parity selects k-step 2c / 2c+1.
__device__ __forceinline__ i32x4 mkfrag(const f32x16& a, int parity) {
  const int b = parity * 8;
  i32x4 v;
  v.x = (int)pkr(a[b + 0], a[b + 1]);
  v.y = (int)pkr(a[b + 2], a[b + 3]);
  v.z = (int)pkr(a[b + 4], a[b + 5]);
  v.w = (int)pkr(a[b + 6], a[b + 7]);
  return v;
}

__device__ __forceinline__ int phi(int k) {  // swap bits 2 and 3
  return (k & ~12) | ((k & 4) << 1) | ((k & 8) >> 1);
}

// Element-parallel prep: one thread per blob element (25088).
__global__ __launch_bounds__(256) void prep_kernel(
    const float* __restrict__ W1, const float* __restrict__ b1,
    const float* __restrict__ W2, const float* __restrict__ b2,
    const float* __restrict__ W3, const float* __restrict__ b3,
    unsigned short* __restrict__ blob) {
  int idx = blockIdx.x * 256 + threadIdx.x;
  if (idx >= 25088) return;
  int j = idx & 7;
  float v;
  if (idx < 18432) {  // W2: chunk = (c*9+s)*64 + lane, k permuted by phi
    int chunk = idx >> 3;
    int lane = chunk & 63;
    int cs = chunk >> 6;
    int c = cs / 9, s = cs - 9 * c;
    int h = lane >> 5, f = 32 * c + (lane & 31);
    int k = 16 * s + 8 * h + j;
    v = (k < 128) ? W2[phi(k) * 128 + f] : ((k == 128) ? b2[f] : 0.f);
  } else if (idx < 23040) {  // W3 (M padded 3->32), k permuted by phi
    int r = (idx - 18432) >> 3;
    int lane = r & 63, s = r >> 6;
    int h = lane >> 5, f = lane & 31;
    int k = 16 * s + 8 * h + j;
    v = 0.f;
    if (f < 3) v = (k < 128) ? W3[phi(k) * 3 + f] : ((k == 128) ? b3[f] : 0.f);
  } else {  // W1 (K padded 5(+bias)->16), natural
    int r = (idx - 23040) >> 3;
    int lane = r & 63, c = r >> 6;
    int h = lane >> 5, f = 32 * c + (lane & 31);
    int k = 8 * h + j;
    v = (k < 5) ? W1[k * 128 + f] : ((k == 5) ? b1[f] : 0.f);
  }
  blob[idx] = f2b(v);
}

// Non-persistent: 2048 blocks of 256 (one 256-row tile each), 3 blocks/CU.
__global__ __launch_bounds__(256, 3) void dyn_kernel(
    const float* __restrict__ S, const float* __restrict__ A,
    const unsigned short* __restrict__ blob, float* __restrict__ out) {
  __shared__ __align__(16) unsigned short lds[25088];
  const int tid = threadIdx.x;
  const int lane = tid & 63;
  const int wv = tid >> 6;
  const int h = lane >> 5;
  const int ln = lane & 31;

  {  // async stage whole frag blob (50 KB) into LDS; drained at the barrier.
    const GLOBAL_AS char* g = (const GLOBAL_AS char*)blob;
    LDS_AS char* l = (LDS_AS char*)lds;
#pragma unroll
    for (int i = 0; i < 12; ++i)
      __builtin_amdgcn_global_load_lds(
          (const GLOBAL_AS unsigned*)(g + 16 * (tid + 256 * i)),
          (LDS_AS unsigned*)(l + 16 * (tid + 256 * i)), 16, 0, 0);
    if (tid < 64)  // chunks 3072..3135
      __builtin_amdgcn_global_load_lds(
          (const GLOBAL_AS unsigned*)(g + 16 * (tid + 3072)),
          (LDS_AS unsigned*)(l + 16 * (tid + 3072)), 16, 0, 0);
  }

  const int r0 = blockIdx.x * 256 + wv * 64;  // wave covers rows [r0, r0+64)
  const int row = r0 + lane;

  const float sx = S[row * 3 + 0], sy = S[row * 3 + 1], sz = S[row * 3 + 2];
  const float2 av = ((const float2*)A)[row];
  const float ax = av.x, ay = av.y;

  // ---- reward, fp32, overlapped with the staging DMA ----
  {
    float quad = 30.f * ((sx - ax) * (sx - ax) + (sy - ay) * (sy - ay));
    const float OX[6] = {0.f, 0.f, 0.f, 0.f, 0.f, -0.8f};
    const float OY[6] = {0.f, 0.2f, 0.4f, 0.6f, 0.8f, -0.8f};
    const float C2 = 20.609622817083824f;  // log2(e)/(2*VAR)
    float gs = 0.f;
#pragma unroll
    for (int i = 0; i < 6; ++i) {
      float dx = sx - OX[i], dy = sy - OY[i];
      gs += __builtin_amdgcn_exp2f(-(dx * dx + dy * dy) * C2);
    }
    const float IB = 801.5624162594774f;  // log2(e)/(2*SIG^2)
    float e1 = sx + 1.5f, e2 = sx - 1.5f, e3 = sy - 1.0f, e4 = sy + 1.0f;
    float bnd = __builtin_amdgcn_exp2f(-e1 * e1 * IB) +
                __builtin_amdgcn_exp2f(-e2 * e2 * IB) +
                __builtin_amdgcn_exp2f(-e3 * e3 * IB) +
                __builtin_amdgcn_exp2f(-e4 * e4 * IB);
    out[3 * B_N + row] =
        -(quad + 454.72840883398667f * gs + 132.98076013381091f * bnd);
  }

  __syncthreads();  // drains the weight DMA

  const i32x4* w2p = (const i32x4*)lds;            // (c*9+s)*64 + lane
  const i32x4* w3p = (const i32x4*)(lds + 18432);  // s*64 + lane
  const i32x4* w1p = (const i32x4*)(lds + 23040);  // c*64 + lane

  // x frags for both 32-sample halves (t=1 data via lane-pair shuffle).
  // NO lane masking: A's k-pad slots are exactly +0 and these B values are
  // finite, so the products vanish regardless of h.
  const float u0 = __shfl_xor(sx, 32, 64), u1 = __shfl_xor(sy, 32, 64);
  const float u2 = __shfl_xor(sz, 32, 64), u3 = __shfl_xor(ax, 32, 64);
  const float u4 = __shfl_xor(ay, 32, 64);

  i32x4 xf[2];
  xf[0].x = (int)pk2(sx, sy);
  xf[0].y = (int)pk2(sz, ax);
  xf[0].z = (int)pk2(ay, 1.0f);
  xf[0].w = 0;
  xf[1].x = (int)pk2(u0, u1);
  xf[1].y = (int)pk2(u2, u3);
  xf[1].z = (int)pk2(u4, 1.0f);
  xf[1].w = 0;

  i32x4 bias_frag;  // only the k==128 slot (h=0,j=0) meets nonzero A
  bias_frag.x = 0x3F80;
  bias_frag.y = 0; bias_frag.z = 0; bias_frag.w = 0;

  const f32x16 ZERO = zero16();  // single shared C-seed for all chains

  // ---- L1 + pack (per half; one acc1 set live at a time) ----
  i32x4 bf2[2][8];
#pragma unroll
  for (int t = 0; t < 2; ++t) {
    bf16x8 xb = __builtin_bit_cast(bf16x8, xf[t]);
    f32x16 acc1[4];
#pragma unroll
    for (int c = 0; c < 4; ++c)
      acc1[c] = __builtin_amdgcn_mfma_f32_32x32x16_bf16(
          __builtin_bit_cast(bf16x8, w1p[c * 64 + lane]), xb, ZERO, 0, 0, 0);
#pragma unroll
    for (int s = 0; s < 8; ++s) bf2[t][s] = mkfrag(acc1[s >> 1], s & 1);
  }

  // ---- L2 in 4 c-groups, each feeding L3 immediately (caps live regs) ----
  f32x16 acc3[2];
#pragma unroll
  for (int g = 0; g < 4; ++g) {
    f32x16 a2g[2];
    {  // s = 0 seeds the chains from ZERO (D != C)
      bf16x8 aa = __builtin_bit_cast(bf16x8, w2p[(g * 9 + 0) * 64 + lane]);
      a2g[0] = __builtin_amdgcn_mfma_f32_32x32x16_bf16(
          aa, __builtin_bit_cast(bf16x8, bf2[0][0]), ZERO, 0, 0, 0);
      a2g[1] = __builtin_amdgcn_mfma_f32_32x32x16_bf16(
          aa, __builtin_bit_cast(bf16x8, bf2[1][0]), ZERO, 0, 0, 0);
    }
#pragma unroll
    for (int s = 1; s < 9; ++s) {
      bf16x8 aa = __builtin_bit_cast(bf16x8, w2p[(g * 9 + s) * 64 + lane]);
      bf16x8 b0 = __builtin_bit_cast(bf16x8, s < 8 ? bf2[0][s] : bias_frag);
      bf16x8 b1 = __builtin_bit_cast(bf16x8, s < 8 ? bf2[1][s] : bias_frag);
      a2g[0] = __builtin_amdgcn_mfma_f32_32x32x16_bf16(aa, b0, a2g[0], 0, 0, 0);
      a2g[1] = __builtin_amdgcn_mfma_f32_32x32x16_bf16(aa, b1, a2g[1], 0, 0, 0);
    }
#pragma unroll
    for (int p = 0; p < 2; ++p) {
      bf16x8 w3f = __builtin_bit_cast(bf16x8, w3p[(2 * g + p) * 64 + lane]);
#pragma unroll
      for (int t = 0; t < 2; ++t) {
        i32x4 fr = mkfrag(a2g[t], p);
        if (g == 0 && p == 0)  // compile-time: seed acc3 from ZERO
          acc3[t] = __builtin_amdgcn_mfma_f32_32x32x16_bf16(
              w3f, __builtin_bit_cast(bf16x8, fr), ZERO, 0, 0, 0);
        else
          acc3[t] = __builtin_amdgcn_mfma_f32_32x32x16_bf16(
              w3f, __builtin_bit_cast(bf16x8, fr), acc3[t], 0, 0, 0);
      }
    }
  }
  {  // L3 bias k-step (s=8)
    bf16x8 w3f = __builtin_bit_cast(bf16x8, w3p[8 * 64 + lane]);
    bf16x8 bb = __builtin_bit_cast(bf16x8, bias_frag);
    acc3[0] = __builtin_amdgcn_mfma_f32_32x32x16_bf16(w3f, bb, acc3[0], 0, 0, 0);
    acc3[1] = __builtin_amdgcn_mfma_f32_32x32x16_bf16(w3f, bb, acc3[1], 0, 0, 0);
  }

  // ---- store s_next: C-layout h=0 lanes, regs 0..2 ----
  if (h == 0) {
#pragma unroll
    for (int t = 0; t < 2; ++t) {
      int r = r0 + 32 * t + ln;
      float* p = out + r * 3;
      p[0] = acc3[t][0];
      p[1] = acc3[t][1];
      p[2] = acc3[t][2];
    }
  }
}

extern "C" void kernel_launch(void* const* d_in, const int* in_sizes, int n_in,
                              void* d_out, int out_size, void* d_ws, size_t ws_size,
                              hipStream_t stream) {
  const float* S = (const float*)d_in[0];
  const float* A = (const float*)d_in[1];
  const float* W1 = (const float*)d_in[2];
  const float* b1 = (const float*)d_in[3];
  const float* W2 = (const float*)d_in[4];
  const float* b2 = (const float*)d_in[5];
  const float* W3 = (const float*)d_in[6];
  const float* b3 = (const float*)d_in[7];
  unsigned short* blob = (unsigned short*)d_ws;
  float* out = (float*)d_out;

  prep_kernel<<<dim3(98), dim3(256), 0, stream>>>(W1, b1, W2, b2, W3, b3, blob);
  dyn_kernel<<<dim3(B_N / 256), dim3(256), 0, stream>>>(S, A, blob, out);
}